// Round 8
// baseline (477.085 us; speedup 1.0000x reference)
//
#include <hip/hip_runtime.h>
#include <hip/hip_bf16.h>
#include <math.h>

#define N_NODES 20000
#define N_EDGES 320000
#define DIN 768
#define F1 1024   // H1*C1
#define H1 8
#define C1 128
#define F2 128
#define NEG_SLOPE 0.2f
#define BN_EPS 1e-5f
#define RESCALE_THR 8.0f

typedef __attribute__((ext_vector_type(8))) __bf16 bf16x8;
typedef __attribute__((ext_vector_type(4))) float f32x4;

__device__ __forceinline__ float leaky(float x) { return x > 0.f ? x : NEG_SLOPE * x; }

__device__ __forceinline__ unsigned short f2bu(float x) {
  __hip_bfloat16 b = __float2bfloat16(x);
  return *(unsigned short*)&b;
}
__device__ __forceinline__ float b2f(unsigned short u) {
  return __uint_as_float(((unsigned)u) << 16);
}
__device__ __forceinline__ unsigned pack2(float lo, float hi) {
  return (unsigned)f2bu(lo) | ((unsigned)f2bu(hi) << 16);
}

__device__ __forceinline__ void async_copy16(void* lds, const void* g) {
  __builtin_amdgcn_global_load_lds(
      (const __attribute__((address_space(1))) unsigned int*)g,
      (__attribute__((address_space(3))) unsigned int*)lds, 16, 0, 0);
}

// ---------------- edge_index repack + dst histogram (fused) ----------------
__global__ void repack_hist_kernel(const int* raw, int* ei32, int* deg) {
  int is64 = (raw[1] == 0 && raw[3] == 0 && raw[5] == 0 && raw[7] == 0) ? 1 : 0;
  int e = blockIdx.x * blockDim.x + threadIdx.x;
  if (e < 2 * N_EDGES) {
    int v = is64 ? raw[2 * e] : raw[e];
    ei32[e] = v;
    if (e >= N_EDGES) atomicAdd(&deg[v], 1);   // dst half
  }
}

// single-block scan: 1024 threads x 20 nodes each, 2 barriers total
#define NPT 20
__global__ __launch_bounds__(1024) void scan_kernel(const int* __restrict__ deg,
                                                    int* __restrict__ off,
                                                    int* __restrict__ cursor) {
  __shared__ int wsum[16];
  int tid = threadIdx.x;
  int lane = tid & 63, wv = tid >> 6;
  int base = tid * NPT;
  int loc[NPT];
  int run = 0;
#pragma unroll
  for (int k = 0; k < NPT; ++k) {
    int i = base + k;
    int v = (i < N_NODES) ? deg[i] : 0;
    loc[k] = run;
    run += v;
  }
  int incl = run;
  for (int sh = 1; sh < 64; sh <<= 1) {
    int t = __shfl_up(incl, sh, 64);
    if (lane >= sh) incl += t;
  }
  if (lane == 63) wsum[wv] = incl;
  __syncthreads();
  if (wv == 0 && lane < 16) {
    int v = wsum[lane];
    for (int sh = 1; sh < 16; sh <<= 1) {
      int t = __shfl_up(v, sh, 16);
      if (lane >= sh) v += t;
    }
    wsum[lane] = v;
  }
  __syncthreads();
  int wbase = (wv > 0) ? wsum[wv - 1] : 0;
  int tbase = wbase + incl - run;
#pragma unroll
  for (int k = 0; k < NPT; ++k) {
    int i = base + k;
    if (i < N_NODES) {
      int o = tbase + loc[k];
      off[i] = o;
      cursor[i] = o;
    }
  }
  if (tid == 1023) off[N_NODES] = wbase + incl;
}

__global__ void scatter_kernel(const int* ei, int* cursor, int* elist) {
  int e = blockIdx.x * blockDim.x + threadIdx.x;
  if (e < N_EDGES) {
    int dst = ei[N_EDGES + e];
    int p = atomicAdd(&cursor[dst], 1);
    elist[p] = ei[e];
  }
}

// ---------------- fp32 -> bf16 convert ----------------
__global__ void f2b_kernel(const float* __restrict__ in, unsigned short* __restrict__ out,
                           size_t n4) {
  size_t i = (size_t)blockIdx.x * blockDim.x + threadIdx.x;
  size_t stride = (size_t)gridDim.x * blockDim.x;
  for (; i < n4; i += stride) {
    float4 v = ((const float4*)in)[i];
    ushort4 u;
    u.x = f2bu(v.x); u.y = f2bu(v.y); u.z = f2bu(v.z); u.w = f2bu(v.w);
    ((ushort4*)out)[i] = u;
  }
}

// ---------------- transpose + convert: W[K][N] fp32 -> WT[N][K] bf16 ----------------
__global__ void transpose_b_kernel(const float* __restrict__ W, unsigned short* __restrict__ WT,
                                   int K, int N) {
  __shared__ float t[32][33];
  int k0 = blockIdx.y * 32, n0 = blockIdx.x * 32;
  int tx = threadIdx.x & 31, ty = threadIdx.x >> 5;
  for (int i = 0; i < 32; i += 8)
    t[ty + i][tx] = W[(size_t)(k0 + ty + i) * N + n0 + tx];
  __syncthreads();
  for (int i = 0; i < 32; i += 8)
    WT[(size_t)(n0 + ty + i) * K + k0 + tx] = f2bu(t[tx][ty + i]);
}

// ---------------- bf16 MFMA GEMM + fused att-logit epilogue ----------------
#define GBM 128
#define GBN 128
#define GBK 64
template <int H, int SWZ>
__global__ __launch_bounds__(256) void mfma_gemm_att_kernel(
    const unsigned short* __restrict__ A,   // [M][K] bf16
    const unsigned short* __restrict__ BT,  // [N][K] bf16
    unsigned short* __restrict__ C,         // [M][N] bf16
    const float* __restrict__ att_src,      // [N]
    const float* __restrict__ att_dst,      // [N]
    float* __restrict__ as_out,             // [M][H]
    float* __restrict__ ad_out,             // [M][H]
    int M, int N, int K) {
  __shared__ __hip_bfloat16 As[GBM][GBK];
  __shared__ __hip_bfloat16 Bs[GBN][GBK];
  __shared__ float sred[128][2];
  __shared__ float dred[128][2];
  int bx, by;
  if (SWZ) {
    int bid = blockIdx.x;
    int pl = bid & 7, c = (bid >> 3) & 7, ph = bid >> 6;
    int p = ph * 8 + pl;
    if (p * GBM >= M) return;
    by = p; bx = c;
  } else {
    bx = blockIdx.x; by = blockIdx.y;
  }
  int tid = threadIdx.x;
  int lane = tid & 63, wid = tid >> 6;
  int wr = wid >> 1, wc = wid & 1;                // 2x2 wave grid, 64x64 out each
  int row0 = by * GBM, col0 = bx * GBN;
  int head = bx;                                  // col-tile == head (H tiles)
  int l16 = lane & 15, l4 = lane >> 4;
  f32x4 acc[4][4] = {};
  for (int k0 = 0; k0 < K; k0 += GBK) {
#pragma unroll
    for (int j = 0; j < 4; ++j) {
      int c = j * 256 + tid;
      int r = c >> 3, kk = (c & 7) << 3;
      int ga = row0 + r; if (ga >= M) ga = M - 1;
      async_copy16(&As[r][kk], A + (size_t)ga * K + k0 + kk);
      async_copy16(&Bs[r][kk], BT + (size_t)(col0 + r) * K + k0 + kk);
    }
    __syncthreads();
#pragma unroll
    for (int ks = 0; ks < 2; ++ks) {
      bf16x8 af[4], bfr[4];
#pragma unroll
      for (int i = 0; i < 4; ++i)
        af[i] = *(const bf16x8*)&As[wr * 64 + i * 16 + l16][ks * 32 + l4 * 8];
#pragma unroll
      for (int j = 0; j < 4; ++j)
        bfr[j] = *(const bf16x8*)&Bs[wc * 64 + j * 16 + l16][ks * 32 + l4 * 8];
#pragma unroll
      for (int i = 0; i < 4; ++i)
#pragma unroll
        for (int j = 0; j < 4; ++j)
          acc[i][j] = __builtin_amdgcn_mfma_f32_16x16x32_bf16(af[i], bfr[j], acc[i][j], 0, 0, 0);
    }
    __syncthreads();
  }
  // ---- C store (bf16): col=lane&15, row=(lane>>4)*4+r ----
#pragma unroll
  for (int i = 0; i < 4; ++i) {
#pragma unroll
    for (int j = 0; j < 4; ++j) {
#pragma unroll
      for (int r = 0; r < 4; ++r) {
        int row = row0 + wr * 64 + i * 16 + l4 * 4 + r;
        int col = col0 + wc * 64 + j * 16 + l16;
        if (row < M) C[(size_t)row * N + col] = f2bu(acc[i][j][r]);
      }
    }
  }
  // ---- fused attention logits from fp32 accumulators ----
  float avs[4], avd[4];
#pragma unroll
  for (int j = 0; j < 4; ++j) {
    int col = col0 + wc * 64 + j * 16 + l16;
    avs[j] = att_src[col];
    avd[j] = att_dst[col];
  }
#pragma unroll
  for (int i = 0; i < 4; ++i) {
#pragma unroll
    for (int r = 0; r < 4; ++r) {
      float ps = 0.f, pd = 0.f;
#pragma unroll
      for (int j = 0; j < 4; ++j) { ps += acc[i][j][r] * avs[j]; pd += acc[i][j][r] * avd[j]; }
#pragma unroll
      for (int mk = 1; mk < 16; mk <<= 1) {
        ps += __shfl_xor(ps, mk, 64);
        pd += __shfl_xor(pd, mk, 64);
      }
      if (l16 == 0) {
        int lr = wr * 64 + i * 16 + l4 * 4 + r;
        sred[lr][wc] = ps;
        dred[lr][wc] = pd;
      }
    }
  }
  __syncthreads();
  if (tid < 128) {
    int row = row0 + tid;
    if (row < M) {
      as_out[(size_t)row * H + head] = sred[tid][0] + sred[tid][1];
      ad_out[(size_t)row * H + head] = dred[tid][0] + dred[tid][1];
    }
  }
}

// ---------------- gather layer 1: head-partitioned (XCD channel-slicing) ----------------
// grid (H1, N_NODES): block = (head, node); linear id = head + 8*node so
// XCD = head -> each XCD's L2 only ever holds h1's 256B slice of one head
// (5.1 MB footprint vs 41 MB). Edge order identical to previous rounds.
#define G1_LOAD(i, rv, ev)                                                     \
  if ((i) < e) {                                                               \
    int ssrc = elist[(i)];                                                     \
    ev = leaky(as1[ssrc * H1 + head] + ad);                                    \
    rv = *(const unsigned*)(h1 + (size_t)ssrc * F1 + cb);                      \
  }
#define G1_CONSUME(u, el)                                                      \
  {                                                                            \
    float w;                                                                   \
    if (el > m + RESCALE_THR) {                                                \
      float rr = __expf(m - el);                                               \
      z *= rr; a0 *= rr; a1 *= rr;                                             \
      m = el; w = 1.f;                                                         \
    } else {                                                                   \
      w = __expf(el - m);                                                      \
    }                                                                          \
    z += w;                                                                    \
    a0 += w * __uint_as_float(u << 16);                                        \
    a1 += w * __uint_as_float(u & 0xffff0000u);                                \
  }

__global__ __launch_bounds__(64) void gather1_kernel(const unsigned short* __restrict__ h1,
                                                     const float* __restrict__ as1,
                                                     const float* __restrict__ ad1,
                                                     const int* __restrict__ off,
                                                     const int* __restrict__ elist,
                                                     const float* __restrict__ b1,
                                                     unsigned short* __restrict__ out1) {
  int head = blockIdx.x;           // 0..7  -> XCD affinity
  int node = blockIdx.y;           // 0..19999
  int tid = threadIdx.x;           // 64 lanes, 2 channels each
  int cb = head * C1 + tid * 2;    // channel offset in [0,F1)
  const float ad = ad1[node * H1 + head];
  int s = off[node], e = off[node + 1];
  float m = leaky(as1[node * H1 + head] + ad);
  float z = 1.f;
  float a0, a1;
  {
    unsigned u = *(const unsigned*)(h1 + (size_t)node * F1 + cb);
    a0 = __uint_as_float(u << 16); a1 = __uint_as_float(u & 0xffff0000u);
  }
  unsigned ra0 = 0, ra1 = 0, ra2 = 0, ra3 = 0;
  float ea0 = 0.f, ea1 = 0.f, ea2 = 0.f, ea3 = 0.f;
  G1_LOAD(s + 0, ra0, ea0)
  G1_LOAD(s + 1, ra1, ea1)
  G1_LOAD(s + 2, ra2, ea2)
  G1_LOAD(s + 3, ra3, ea3)
  for (int base = s; base < e; base += 4) {
    unsigned rb0 = 0, rb1 = 0, rb2 = 0, rb3 = 0;
    float eb0 = 0.f, eb1 = 0.f, eb2 = 0.f, eb3 = 0.f;
    int nb = base + 4;
    G1_LOAD(nb + 0, rb0, eb0)
    G1_LOAD(nb + 1, rb1, eb1)
    G1_LOAD(nb + 2, rb2, eb2)
    G1_LOAD(nb + 3, rb3, eb3)
    G1_CONSUME(ra0, ea0)
    if (base + 1 < e) G1_CONSUME(ra1, ea1)
    if (base + 2 < e) G1_CONSUME(ra2, ea2)
    if (base + 3 < e) G1_CONSUME(ra3, ea3)
    ra0 = rb0; ra1 = rb1; ra2 = rb2; ra3 = rb3;
    ea0 = eb0; ea1 = eb1; ea2 = eb2; ea3 = eb3;
  }
  float inv = 1.f / z;
  float2 bv = *(const float2*)(b1 + cb);
  unsigned o = pack2(a0 * inv + bv.x, a1 * inv + bv.y);
  *(unsigned*)(out1 + (size_t)node * F1 + cb) = o;
}

// ---------------- BN statistics, bf16 input ----------------
__global__ void bnstats_bf16_kernel(const unsigned short* __restrict__ x,
                                    float* __restrict__ sums,
                                    int nrows, int F, int rowsPerBlock) {
  int tid = threadIdx.x;
  int c = tid * 4;
  int r0 = blockIdx.x * rowsPerBlock;
  int rend = min(r0 + rowsPerBlock, nrows);
  float s0 = 0.f, s1 = 0.f, s2 = 0.f, s3 = 0.f;
  float q0 = 0.f, q1 = 0.f, q2 = 0.f, q3 = 0.f;
  for (int r = r0; r < rend; ++r) {
    ushort4 u = *(const ushort4*)(x + (size_t)r * F + c);
    float v0 = b2f(u.x), v1 = b2f(u.y), v2 = b2f(u.z), v3 = b2f(u.w);
    s0 += v0; s1 += v1; s2 += v2; s3 += v3;
    q0 += v0 * v0; q1 += v1 * v1; q2 += v2 * v2; q3 += v3 * v3;
  }
  atomicAdd(&sums[c + 0], s0); atomicAdd(&sums[c + 1], s1);
  atomicAdd(&sums[c + 2], s2); atomicAdd(&sums[c + 3], s3);
  atomicAdd(&sums[F + c + 0], q0); atomicAdd(&sums[F + c + 1], q1);
  atomicAdd(&sums[F + c + 2], q2); atomicAdd(&sums[F + c + 3], q3);
}

// fp32-input variant (layer 2, small)
template <int CPT>
__global__ void bnstats_kernel(const float* __restrict__ x, float* __restrict__ sums,
                               int nrows, int F, int rowsPerBlock) {
  int tid = threadIdx.x;
  int r0 = blockIdx.x * rowsPerBlock;
  int rend = min(r0 + rowsPerBlock, nrows);
  float s[CPT], q[CPT];
#pragma unroll
  for (int k = 0; k < CPT; ++k) { s[k] = 0.f; q[k] = 0.f; }
  for (int r = r0; r < rend; ++r) {
    const float* row = x + (size_t)r * F;
#pragma unroll
    for (int k = 0; k < CPT; ++k) {
      float v = row[tid + k * blockDim.x];
      s[k] += v; q[k] += v * v;
    }
  }
#pragma unroll
  for (int k = 0; k < CPT; ++k) {
    atomicAdd(&sums[tid + k * blockDim.x], s[k]);
    atomicAdd(&sums[F + tid + k * blockDim.x], q[k]);
  }
}

__global__ void bnfinal_kernel(const float* __restrict__ sums, const float* __restrict__ g,
                               const float* __restrict__ be, float* __restrict__ ss, int F) {
  int c = blockIdx.x * blockDim.x + threadIdx.x;
  if (c < F) {
    float mu = sums[c] * (1.f / N_NODES);
    float var = sums[F + c] * (1.f / N_NODES) - mu * mu;
    float sc = g[c] * rsqrtf(var + BN_EPS);
    ss[c] = sc;
    ss[F + c] = be[c] - mu * sc;
  }
}

// BN apply + ELU, bf16 in-place (layer 1, feeds GEMM2)
__global__ void bnapply_bf16_kernel(unsigned short* __restrict__ x, const float* __restrict__ ss,
                                    int F, size_t total4) {
  size_t i = (size_t)blockIdx.x * blockDim.x + threadIdx.x;
  size_t stride = (size_t)gridDim.x * blockDim.x;
  for (; i < total4; i += stride) {
    int c = (int)((i * 4) & (size_t)(F - 1));
    ushort4 u = ((ushort4*)x)[i];
    float v0 = b2f(u.x) * ss[c + 0] + ss[F + c + 0];
    float v1 = b2f(u.y) * ss[c + 1] + ss[F + c + 1];
    float v2 = b2f(u.z) * ss[c + 2] + ss[F + c + 2];
    float v3 = b2f(u.w) * ss[c + 3] + ss[F + c + 3];
    v0 = v0 > 0.f ? v0 : expm1f(v0);
    v1 = v1 > 0.f ? v1 : expm1f(v1);
    v2 = v2 > 0.f ? v2 : expm1f(v2);
    v3 = v3 > 0.f ? v3 : expm1f(v3);
    u.x = f2bu(v0); u.y = f2bu(v1); u.z = f2bu(v2); u.w = f2bu(v3);
    ((ushort4*)x)[i] = u;
  }
}

// ---------------- gather layer 2: online softmax, chunk-4 double-buffered ----------------
#define G2_LOAD(i, rv, ev)                                                     \
  if ((i) < e) {                                                               \
    int ssrc = elist[(i)];                                                     \
    ev = leaky(as2[ssrc] + ad);                                                \
    rv = *(const unsigned*)(h2 + (size_t)ssrc * F2 + tid * 2);                 \
  }
#define G2_CONSUME(u, el)                                                      \
  {                                                                            \
    float w;                                                                   \
    if (el > m + RESCALE_THR) {                                                \
      float rr = __expf(m - el);                                               \
      z *= rr; a0 *= rr; a1 *= rr;                                             \
      m = el; w = 1.f;                                                         \
    } else {                                                                   \
      w = __expf(el - m);                                                      \
    }                                                                          \
    z += w;                                                                    \
    a0 += w * __uint_as_float(u << 16);                                        \
    a1 += w * __uint_as_float(u & 0xffff0000u);                                \
  }

__global__ __launch_bounds__(64) void gather2_kernel(const unsigned short* __restrict__ h2,
                                                     const float* __restrict__ as2,
                                                     const float* __restrict__ ad2,
                                                     const int* __restrict__ off,
                                                     const int* __restrict__ elist,
                                                     const float* __restrict__ b2,
                                                     float* __restrict__ out2) {
  int node = blockIdx.x;
  int tid = threadIdx.x;          // 64, 2 channels each
  const float ad = ad2[node];
  int s = off[node], e = off[node + 1];
  float m = leaky(as2[node] + ad);
  float z = 1.f;
  float a0, a1;
  {
    unsigned u = *(const unsigned*)(h2 + (size_t)node * F2 + tid * 2);
    a0 = __uint_as_float(u << 16); a1 = __uint_as_float(u & 0xffff0000u);
  }
  unsigned ra0 = 0, ra1 = 0, ra2 = 0, ra3 = 0;
  float ea0 = 0.f, ea1 = 0.f, ea2 = 0.f, ea3 = 0.f;
  G2_LOAD(s + 0, ra0, ea0)
  G2_LOAD(s + 1, ra1, ea1)
  G2_LOAD(s + 2, ra2, ea2)
  G2_LOAD(s + 3, ra3, ea3)
  for (int base = s; base < e; base += 4) {
    unsigned rb0 = 0, rb1 = 0, rb2 = 0, rb3 = 0;
    float eb0 = 0.f, eb1 = 0.f, eb2 = 0.f, eb3 = 0.f;
    int nb = base + 4;
    G2_LOAD(nb + 0, rb0, eb0)
    G2_LOAD(nb + 1, rb1, eb1)
    G2_LOAD(nb + 2, rb2, eb2)
    G2_LOAD(nb + 3, rb3, eb3)
    G2_CONSUME(ra0, ea0)
    if (base + 1 < e) G2_CONSUME(ra1, ea1)
    if (base + 2 < e) G2_CONSUME(ra2, ea2)
    if (base + 3 < e) G2_CONSUME(ra3, ea3)
    ra0 = rb0; ra1 = rb1; ra2 = rb2; ra3 = rb3;
    ea0 = eb0; ea1 = eb1; ea2 = eb2; ea3 = eb3;
  }
  float inv = 1.f / z;
  float2 o = make_float2(a0 * inv + b2[tid * 2 + 0], a1 * inv + b2[tid * 2 + 1]);
  *(float2*)(out2 + (size_t)node * F2 + tid * 2) = o;
}

// ---------------- classifier head (fused BN2 apply + ELU) ----------------
__global__ __launch_bounds__(64) void cls_kernel(const float* __restrict__ h,
                                                 const float* __restrict__ ss2,
                                                 const float* __restrict__ Wc1,
                                                 const float* __restrict__ bc1,
                                                 const float* __restrict__ Wc2,
                                                 const float* __restrict__ bc2,
                                                 float* __restrict__ out) {
  __shared__ float hl[128];
  int node = blockIdx.x;
  int tid = threadIdx.x;          // 64
  {
    float v = h[(size_t)node * F2 + tid] * ss2[tid] + ss2[F2 + tid];
    v = v > 0.f ? v : expm1f(v);
    hl[tid] = v;
    float v2 = h[(size_t)node * F2 + 64 + tid] * ss2[64 + tid] + ss2[F2 + 64 + tid];
    v2 = v2 > 0.f ? v2 : expm1f(v2);
    hl[tid + 64] = v2;
  }
  __syncthreads();
  float acc = bc1[tid];
#pragma unroll
  for (int k = 0; k < 128; ++k) acc += hl[k] * Wc1[k * 64 + tid];
  acc = fmaxf(acc, 0.f);
  float2 w = *(const float2*)(Wc2 + tid * 2);
  float o0 = acc * w.x, o1 = acc * w.y;
  for (int sh = 32; sh >= 1; sh >>= 1) {
    o0 += __shfl_down(o0, sh, 64);
    o1 += __shfl_down(o1, sh, 64);
  }
  if (tid == 0) {
    out[node * 2 + 0] = o0 + bc2[0];
    out[node * 2 + 1] = o1 + bc2[1];
  }
}

extern "C" void kernel_launch(void* const* d_in, const int* in_sizes, int n_in,
                              void* d_out, int out_size, void* d_ws, size_t ws_size,
                              hipStream_t stream) {
  const float* x        = (const float*)d_in[0];
  const int*   ei_raw   = (const int*)d_in[1];
  const float* W1       = (const float*)d_in[2];
  const float* att_src1 = (const float*)d_in[3];
  const float* att_dst1 = (const float*)d_in[4];
  const float* b1       = (const float*)d_in[5];
  const float* W2       = (const float*)d_in[6];
  const float* att_src2 = (const float*)d_in[7];
  const float* att_dst2 = (const float*)d_in[8];
  const float* b2       = (const float*)d_in[9];
  const float* g1       = (const float*)d_in[10];
  const float* be1      = (const float*)d_in[11];
  const float* g2       = (const float*)d_in[12];
  const float* be2      = (const float*)d_in[13];
  const float* Wc1      = (const float*)d_in[14];
  const float* bc1      = (const float*)d_in[15];
  const float* Wc2      = (const float*)d_in[16];
  const float* bc2      = (const float*)d_in[17];
  float* out = (float*)d_out;

  char* ws = (char*)d_ws;
  size_t o = 0;
  unsigned short* h1b   = (unsigned short*)(ws + o); o += (size_t)N_NODES * F1 * 2;  // 40.96 MB
  unsigned short* out1b = (unsigned short*)(ws + o); o += (size_t)N_NODES * F1 * 2;  // 40.96 MB
  unsigned short* xb    = (unsigned short*)(ws + o); o += (size_t)N_NODES * DIN * 2; // 30.72 MB
  unsigned short* h2b   = (unsigned short*)(ws + o); o += (size_t)N_NODES * F2 * 2;  // 5.12 MB
  float* out2  = (float*)(ws + o); o += (size_t)N_NODES * F2 * 4;                    // 10.24 MB
  float* as1   = (float*)(ws + o); o += (size_t)N_NODES * H1 * 4;
  float* ad1   = (float*)(ws + o); o += (size_t)N_NODES * H1 * 4;
  float* as2   = (float*)(ws + o); o += (size_t)N_NODES * 4;
  float* ad2   = (float*)(ws + o); o += (size_t)N_NODES * 4;
  char*  zbase = ws + o;
  float* bnsum1 = (float*)(ws + o); o += F1 * 2 * 4;
  float* bnsum2 = (float*)(ws + o); o += F2 * 2 * 4;
  int*   deg    = (int*)(ws + o); o += (size_t)N_NODES * 4;
  size_t zbytes = (size_t)((ws + o) - zbase);
  int*   offv   = (int*)(ws + o); o += (size_t)(N_NODES + 4) * 4;
  int*   cursor = (int*)(ws + o); o += (size_t)N_NODES * 4;
  int*   elist  = (int*)(ws + o); o += (size_t)N_EDGES * 4;
  float* ss1    = (float*)(ws + o); o += F1 * 2 * 4;
  float* ss2    = (float*)(ws + o); o += F2 * 2 * 4;
  int*   ei32   = (int*)(ws + o); o += (size_t)2 * N_EDGES * 4;
  unsigned short* W1T = (unsigned short*)(ws + o); o += (size_t)F1 * DIN * 2;
  unsigned short* W2T = (unsigned short*)(ws + o); o += (size_t)F2 * F1 * 2;
  (void)ws_size; (void)in_sizes; (void)n_in; (void)out_size;

  hipMemsetAsync((void*)zbase, 0, zbytes, stream);

  // input conversions
  f2b_kernel<<<2048, 256, 0, stream>>>(x, xb, (size_t)N_NODES * DIN / 4);
  {
    dim3 g1d(F1 / 32, DIN / 32);
    transpose_b_kernel<<<g1d, 256, 0, stream>>>(W1, W1T, DIN, F1);
    dim3 g2d(F2 / 32, F1 / 32);
    transpose_b_kernel<<<g2d, 256, 0, stream>>>(W2, W2T, F1, F2);
  }

  // CSR build
  repack_hist_kernel<<<(2 * N_EDGES + 255) / 256, 256, 0, stream>>>(ei_raw, ei32, deg);
  scan_kernel<<<1, 1024, 0, stream>>>(deg, offv, cursor);
  scatter_kernel<<<(N_EDGES + 255) / 256, 256, 0, stream>>>(ei32, cursor, elist);

  // layer 1: h1 = x @ W1 (bf16 MFMA, fused att logits, XCD panel-affinity swizzle)
  {
    int panels = (N_NODES + GBM - 1) / GBM;          // 157
    int grid1 = ((panels + 7) / 8) * 64;             // 1280
    mfma_gemm_att_kernel<H1, 1><<<grid1, 256, 0, stream>>>(
        xb, W1T, h1b, att_src1, att_dst1, as1, ad1, N_NODES, F1, DIN);
  }
  // gather1: head-partitioned grid (8, 20000) -> XCD = head
  gather1_kernel<<<dim3(H1, N_NODES), 64, 0, stream>>>(h1b, as1, ad1, offv, elist, b1, out1b);
  {
    int rows = 79;
    int grid = (N_NODES + rows - 1) / rows;
    bnstats_bf16_kernel<<<grid, 256, 0, stream>>>(out1b, bnsum1, N_NODES, F1, rows);
  }
  bnfinal_kernel<<<(F1 + 255) / 256, 256, 0, stream>>>(bnsum1, g1, be1, ss1, F1);
  bnapply_bf16_kernel<<<2048, 256, 0, stream>>>(out1b, ss1, F1, (size_t)N_NODES * F1 / 4);

  // layer 2: h2 = out1b @ W2 (bf16 MFMA, fused att logits)
  {
    dim3 grid(F2 / GBN, (N_NODES + GBM - 1) / GBM);
    mfma_gemm_att_kernel<1, 0><<<grid, 256, 0, stream>>>(
        out1b, W2T, h2b, att_src2, att_dst2, as2, ad2, N_NODES, F2, F1);
  }
  gather2_kernel<<<N_NODES, 64, 0, stream>>>(h2b, as2, ad2, offv, elist, b2, out2);
  {
    int rows = 79;
    int grid = (N_NODES + rows - 1) / rows;
    bnstats_kernel<1><<<grid, 128, 0, stream>>>(out2, bnsum2, N_NODES, F2, rows);
  }
  bnfinal_kernel<<<1, F2, 0, stream>>>(bnsum2, g2, be2, ss2, F2);

  // classifier (BN2 apply + ELU fused)
  cls_kernel<<<N_NODES, 64, 0, stream>>>(out2, ss2, Wc1, bc1, Wc2, bc2, out);
}

// Round 9
// 461.656 us; speedup vs baseline: 1.0334x; 1.0334x over previous
//
#include <hip/hip_runtime.h>
#include <hip/hip_bf16.h>
#include <math.h>

#define N_NODES 20000
#define N_EDGES 320000
#define DIN 768
#define F1 1024   // H1*C1
#define H1 8
#define C1 128
#define F2 128
#define NEG_SLOPE 0.2f
#define BN_EPS 1e-5f
#define RESCALE_THR 8.0f

typedef __attribute__((ext_vector_type(8))) __bf16 bf16x8;
typedef __attribute__((ext_vector_type(4))) float f32x4;

__device__ __forceinline__ float leaky(float x) { return x > 0.f ? x : NEG_SLOPE * x; }

__device__ __forceinline__ unsigned short f2bu(float x) {
  __hip_bfloat16 b = __float2bfloat16(x);
  return *(unsigned short*)&b;
}
__device__ __forceinline__ float b2f(unsigned short u) {
  return __uint_as_float(((unsigned)u) << 16);
}
__device__ __forceinline__ unsigned pack2(float lo, float hi) {
  return (unsigned)f2bu(lo) | ((unsigned)f2bu(hi) << 16);
}

__device__ __forceinline__ void async_copy16(void* lds, const void* g) {
  __builtin_amdgcn_global_load_lds(
      (const __attribute__((address_space(1))) unsigned int*)g,
      (__attribute__((address_space(3))) unsigned int*)lds, 16, 0, 0);
}

// ---------------- edge_index repack + dst histogram (fused) ----------------
__global__ void repack_hist_kernel(const int* raw, int* ei32, int* deg) {
  int is64 = (raw[1] == 0 && raw[3] == 0 && raw[5] == 0 && raw[7] == 0) ? 1 : 0;
  int e = blockIdx.x * blockDim.x + threadIdx.x;
  if (e < 2 * N_EDGES) {
    int v = is64 ? raw[2 * e] : raw[e];
    ei32[e] = v;
    if (e >= N_EDGES) atomicAdd(&deg[v], 1);   // dst half
  }
}

// single-block scan: 1024 threads x 20 nodes each, 2 barriers total
#define NPT 20
__global__ __launch_bounds__(1024) void scan_kernel(const int* __restrict__ deg,
                                                    int* __restrict__ off,
                                                    int* __restrict__ cursor) {
  __shared__ int wsum[16];
  int tid = threadIdx.x;
  int lane = tid & 63, wv = tid >> 6;
  int base = tid * NPT;
  int loc[NPT];
  int run = 0;
#pragma unroll
  for (int k = 0; k < NPT; ++k) {
    int i = base + k;
    int v = (i < N_NODES) ? deg[i] : 0;
    loc[k] = run;
    run += v;
  }
  int incl = run;
  for (int sh = 1; sh < 64; sh <<= 1) {
    int t = __shfl_up(incl, sh, 64);
    if (lane >= sh) incl += t;
  }
  if (lane == 63) wsum[wv] = incl;
  __syncthreads();
  if (wv == 0 && lane < 16) {
    int v = wsum[lane];
    for (int sh = 1; sh < 16; sh <<= 1) {
      int t = __shfl_up(v, sh, 16);
      if (lane >= sh) v += t;
    }
    wsum[lane] = v;
  }
  __syncthreads();
  int wbase = (wv > 0) ? wsum[wv - 1] : 0;
  int tbase = wbase + incl - run;
#pragma unroll
  for (int k = 0; k < NPT; ++k) {
    int i = base + k;
    if (i < N_NODES) {
      int o = tbase + loc[k];
      off[i] = o;
      cursor[i] = o;
    }
  }
  if (tid == 1023) off[N_NODES] = wbase + incl;
}

__global__ void scatter_kernel(const int* ei, int* cursor, int* elist) {
  int e = blockIdx.x * blockDim.x + threadIdx.x;
  if (e < N_EDGES) {
    int dst = ei[N_EDGES + e];
    int p = atomicAdd(&cursor[dst], 1);
    elist[p] = ei[e];
  }
}

// ---------------- fp32 -> bf16 convert ----------------
__global__ void f2b_kernel(const float* __restrict__ in, unsigned short* __restrict__ out,
                           size_t n4) {
  size_t i = (size_t)blockIdx.x * blockDim.x + threadIdx.x;
  size_t stride = (size_t)gridDim.x * blockDim.x;
  for (; i < n4; i += stride) {
    float4 v = ((const float4*)in)[i];
    ushort4 u;
    u.x = f2bu(v.x); u.y = f2bu(v.y); u.z = f2bu(v.z); u.w = f2bu(v.w);
    ((ushort4*)out)[i] = u;
  }
}

// ---------------- transpose + convert: W[K][N] fp32 -> WT[N][K] bf16 ----------------
__global__ void transpose_b_kernel(const float* __restrict__ W, unsigned short* __restrict__ WT,
                                   int K, int N) {
  __shared__ float t[32][33];
  int k0 = blockIdx.y * 32, n0 = blockIdx.x * 32;
  int tx = threadIdx.x & 31, ty = threadIdx.x >> 5;
  for (int i = 0; i < 32; i += 8)
    t[ty + i][tx] = W[(size_t)(k0 + ty + i) * N + n0 + tx];
  __syncthreads();
  for (int i = 0; i < 32; i += 8)
    WT[(size_t)(n0 + ty + i) * K + k0 + tx] = f2bu(t[tx][ty + i]);
}

// ---------------- bf16 MFMA GEMM + fused att-logit epilogue ----------------
#define GBM 128
#define GBN 128
#define GBK 64
template <int H, int SWZ>
__global__ __launch_bounds__(256) void mfma_gemm_att_kernel(
    const unsigned short* __restrict__ A,   // [M][K] bf16
    const unsigned short* __restrict__ BT,  // [N][K] bf16
    unsigned short* __restrict__ C,         // [M][N] bf16
    const float* __restrict__ att_src,      // [N]
    const float* __restrict__ att_dst,      // [N]
    float* __restrict__ as_out,             // [M][H]
    float* __restrict__ ad_out,             // [M][H]
    int M, int N, int K) {
  __shared__ __hip_bfloat16 As[GBM][GBK];
  __shared__ __hip_bfloat16 Bs[GBN][GBK];
  __shared__ float sred[128][2];
  __shared__ float dred[128][2];
  int bx, by;
  if (SWZ) {
    int bid = blockIdx.x;
    int pl = bid & 7, c = (bid >> 3) & 7, ph = bid >> 6;
    int p = ph * 8 + pl;
    if (p * GBM >= M) return;
    by = p; bx = c;
  } else {
    bx = blockIdx.x; by = blockIdx.y;
  }
  int tid = threadIdx.x;
  int lane = tid & 63, wid = tid >> 6;
  int wr = wid >> 1, wc = wid & 1;                // 2x2 wave grid, 64x64 out each
  int row0 = by * GBM, col0 = bx * GBN;
  int head = bx;                                  // col-tile == head (H tiles)
  int l16 = lane & 15, l4 = lane >> 4;
  f32x4 acc[4][4] = {};
  for (int k0 = 0; k0 < K; k0 += GBK) {
#pragma unroll
    for (int j = 0; j < 4; ++j) {
      int c = j * 256 + tid;
      int r = c >> 3, kk = (c & 7) << 3;
      int ga = row0 + r; if (ga >= M) ga = M - 1;
      async_copy16(&As[r][kk], A + (size_t)ga * K + k0 + kk);
      async_copy16(&Bs[r][kk], BT + (size_t)(col0 + r) * K + k0 + kk);
    }
    __syncthreads();
#pragma unroll
    for (int ks = 0; ks < 2; ++ks) {
      bf16x8 af[4], bfr[4];
#pragma unroll
      for (int i = 0; i < 4; ++i)
        af[i] = *(const bf16x8*)&As[wr * 64 + i * 16 + l16][ks * 32 + l4 * 8];
#pragma unroll
      for (int j = 0; j < 4; ++j)
        bfr[j] = *(const bf16x8*)&Bs[wc * 64 + j * 16 + l16][ks * 32 + l4 * 8];
#pragma unroll
      for (int i = 0; i < 4; ++i)
#pragma unroll
        for (int j = 0; j < 4; ++j)
          acc[i][j] = __builtin_amdgcn_mfma_f32_16x16x32_bf16(af[i], bfr[j], acc[i][j], 0, 0, 0);
    }
    __syncthreads();
  }
  // ---- C store (bf16): col=lane&15, row=(lane>>4)*4+r ----
#pragma unroll
  for (int i = 0; i < 4; ++i) {
#pragma unroll
    for (int j = 0; j < 4; ++j) {
#pragma unroll
      for (int r = 0; r < 4; ++r) {
        int row = row0 + wr * 64 + i * 16 + l4 * 4 + r;
        int col = col0 + wc * 64 + j * 16 + l16;
        if (row < M) C[(size_t)row * N + col] = f2bu(acc[i][j][r]);
      }
    }
  }
  // ---- fused attention logits from fp32 accumulators ----
  float avs[4], avd[4];
#pragma unroll
  for (int j = 0; j < 4; ++j) {
    int col = col0 + wc * 64 + j * 16 + l16;
    avs[j] = att_src[col];
    avd[j] = att_dst[col];
  }
#pragma unroll
  for (int i = 0; i < 4; ++i) {
#pragma unroll
    for (int r = 0; r < 4; ++r) {
      float ps = 0.f, pd = 0.f;
#pragma unroll
      for (int j = 0; j < 4; ++j) { ps += acc[i][j][r] * avs[j]; pd += acc[i][j][r] * avd[j]; }
#pragma unroll
      for (int mk = 1; mk < 16; mk <<= 1) {
        ps += __shfl_xor(ps, mk, 64);
        pd += __shfl_xor(pd, mk, 64);
      }
      if (l16 == 0) {
        int lr = wr * 64 + i * 16 + l4 * 4 + r;
        sred[lr][wc] = ps;
        dred[lr][wc] = pd;
      }
    }
  }
  __syncthreads();
  if (tid < 128) {
    int row = row0 + tid;
    if (row < M) {
      as_out[(size_t)row * H + head] = sred[tid][0] + sred[tid][1];
      ad_out[(size_t)row * H + head] = dred[tid][0] + dred[tid][1];
    }
  }
}

// ---------------- Phase A: per-edge softmax weights (exact, per head) ----------------
// One 64-lane block per node. For each head: wave-reduce max over edge logits
// (incl. self), then write w=exp(el-m) per edge to wexpT[head][CSR index],
// plus wself and 1/z per (node, head).
__global__ __launch_bounds__(64) void alpha1_kernel(const float* __restrict__ as1,
                                                    const float* __restrict__ ad1,
                                                    const int* __restrict__ off,
                                                    const int* __restrict__ elist,
                                                    float* __restrict__ wexpT,   // [H1][E]
                                                    float* __restrict__ zinv,    // [N][H1]
                                                    float* __restrict__ wself) { // [N][H1]
  int node = blockIdx.x;
  int lane = threadIdx.x;
  int s = off[node], e = off[node + 1];
#pragma unroll
  for (int h = 0; h < H1; ++h) {
    float ad = ad1[node * H1 + h];
    float selfl = leaky(as1[node * H1 + h] + ad);
    float m = selfl;
    for (int i = s + lane; i < e; i += 64) {
      float el = leaky(as1[elist[i] * H1 + h] + ad);
      m = fmaxf(m, el);
    }
    for (int sh = 32; sh >= 1; sh >>= 1) m = fmaxf(m, __shfl_xor(m, sh, 64));
    float z = 0.f;
    for (int i = s + lane; i < e; i += 64) {
      float el = leaky(as1[elist[i] * H1 + h] + ad);
      float w = __expf(el - m);
      wexpT[(size_t)h * N_EDGES + i] = w;
      z += w;
    }
    for (int sh = 32; sh >= 1; sh >>= 1) z += __shfl_xor(z, sh, 64);
    float ws = __expf(selfl - m);
    if (lane == 0) {
      zinv[node * H1 + h] = 1.f / (z + ws);
      wself[node * H1 + h] = ws;
    }
  }
}

// ---------------- Phase B: weighted gather, head-partitioned (XCD-local) ----------------
// grid (H1, N_NODES): linear id = head + 8*node -> XCD = head; each XCD's L2
// only holds h1's 256B slice of one head. Inner loop has no exp/branching:
// uniform w + uniform src + 4B row load + 2 FMA, 4-edge unrolled, weights
// preset to 0 for tail edges (unconditional consume).
#define GW_LOAD(i, rv, wv)                                                     \
  if ((i) < e) {                                                               \
    wv = wp[(i)];                                                              \
    rv = *(const unsigned*)(h1 + (size_t)elist[(i)] * F1 + cb);                \
  }
#define GW_CONS(u, wv)                                                         \
  {                                                                            \
    a0 += wv * __uint_as_float(u << 16);                                       \
    a1 += wv * __uint_as_float(u & 0xffff0000u);                               \
  }

__global__ __launch_bounds__(64) void gatherw1_kernel(const unsigned short* __restrict__ h1,
                                                      const float* __restrict__ wexpT,
                                                      const float* __restrict__ zinv,
                                                      const float* __restrict__ wself,
                                                      const int* __restrict__ off,
                                                      const int* __restrict__ elist,
                                                      const float* __restrict__ b1,
                                                      unsigned short* __restrict__ out1) {
  int head = blockIdx.x;           // 0..7 -> XCD affinity
  int node = blockIdx.y;
  int tid = threadIdx.x;           // 64 lanes, 2 channels each
  int cb = head * C1 + tid * 2;
  int s = off[node], e = off[node + 1];
  const float* wp = wexpT + (size_t)head * N_EDGES;
  float a0, a1;
  {
    float ws = wself[node * H1 + head];
    unsigned u = *(const unsigned*)(h1 + (size_t)node * F1 + cb);
    a0 = ws * __uint_as_float(u << 16);
    a1 = ws * __uint_as_float(u & 0xffff0000u);
  }
  unsigned ra0 = 0, ra1 = 0, ra2 = 0, ra3 = 0;
  float wa0 = 0.f, wa1 = 0.f, wa2 = 0.f, wa3 = 0.f;
  GW_LOAD(s + 0, ra0, wa0)
  GW_LOAD(s + 1, ra1, wa1)
  GW_LOAD(s + 2, ra2, wa2)
  GW_LOAD(s + 3, ra3, wa3)
  for (int base = s; base < e; base += 4) {
    unsigned rb0 = 0, rb1 = 0, rb2 = 0, rb3 = 0;
    float wb0 = 0.f, wb1 = 0.f, wb2 = 0.f, wb3 = 0.f;
    int nb = base + 4;
    GW_LOAD(nb + 0, rb0, wb0)
    GW_LOAD(nb + 1, rb1, wb1)
    GW_LOAD(nb + 2, rb2, wb2)
    GW_LOAD(nb + 3, rb3, wb3)
    GW_CONS(ra0, wa0)
    GW_CONS(ra1, wa1)
    GW_CONS(ra2, wa2)
    GW_CONS(ra3, wa3)
    ra0 = rb0; ra1 = rb1; ra2 = rb2; ra3 = rb3;
    wa0 = wb0; wa1 = wb1; wa2 = wb2; wa3 = wb3;
  }
  float inv = zinv[node * H1 + head];
  float2 bv = *(const float2*)(b1 + cb);
  unsigned o = pack2(a0 * inv + bv.x, a1 * inv + bv.y);
  *(unsigned*)(out1 + (size_t)node * F1 + cb) = o;
}

// ---------------- BN statistics, bf16 input ----------------
__global__ void bnstats_bf16_kernel(const unsigned short* __restrict__ x,
                                    float* __restrict__ sums,
                                    int nrows, int F, int rowsPerBlock) {
  int tid = threadIdx.x;
  int c = tid * 4;
  int r0 = blockIdx.x * rowsPerBlock;
  int rend = min(r0 + rowsPerBlock, nrows);
  float s0 = 0.f, s1 = 0.f, s2 = 0.f, s3 = 0.f;
  float q0 = 0.f, q1 = 0.f, q2 = 0.f, q3 = 0.f;
  for (int r = r0; r < rend; ++r) {
    ushort4 u = *(const ushort4*)(x + (size_t)r * F + c);
    float v0 = b2f(u.x), v1 = b2f(u.y), v2 = b2f(u.z), v3 = b2f(u.w);
    s0 += v0; s1 += v1; s2 += v2; s3 += v3;
    q0 += v0 * v0; q1 += v1 * v1; q2 += v2 * v2; q3 += v3 * v3;
  }
  atomicAdd(&sums[c + 0], s0); atomicAdd(&sums[c + 1], s1);
  atomicAdd(&sums[c + 2], s2); atomicAdd(&sums[c + 3], s3);
  atomicAdd(&sums[F + c + 0], q0); atomicAdd(&sums[F + c + 1], q1);
  atomicAdd(&sums[F + c + 2], q2); atomicAdd(&sums[F + c + 3], q3);
}

// fp32-input variant (layer 2, small)
template <int CPT>
__global__ void bnstats_kernel(const float* __restrict__ x, float* __restrict__ sums,
                               int nrows, int F, int rowsPerBlock) {
  int tid = threadIdx.x;
  int r0 = blockIdx.x * rowsPerBlock;
  int rend = min(r0 + rowsPerBlock, nrows);
  float s[CPT], q[CPT];
#pragma unroll
  for (int k = 0; k < CPT; ++k) { s[k] = 0.f; q[k] = 0.f; }
  for (int r = r0; r < rend; ++r) {
    const float* row = x + (size_t)r * F;
#pragma unroll
    for (int k = 0; k < CPT; ++k) {
      float v = row[tid + k * blockDim.x];
      s[k] += v; q[k] += v * v;
    }
  }
#pragma unroll
  for (int k = 0; k < CPT; ++k) {
    atomicAdd(&sums[tid + k * blockDim.x], s[k]);
    atomicAdd(&sums[F + tid + k * blockDim.x], q[k]);
  }
}

__global__ void bnfinal_kernel(const float* __restrict__ sums, const float* __restrict__ g,
                               const float* __restrict__ be, float* __restrict__ ss, int F) {
  int c = blockIdx.x * blockDim.x + threadIdx.x;
  if (c < F) {
    float mu = sums[c] * (1.f / N_NODES);
    float var = sums[F + c] * (1.f / N_NODES) - mu * mu;
    float sc = g[c] * rsqrtf(var + BN_EPS);
    ss[c] = sc;
    ss[F + c] = be[c] - mu * sc;
  }
}

// BN apply + ELU, bf16 in-place (layer 1, feeds GEMM2)
__global__ void bnapply_bf16_kernel(unsigned short* __restrict__ x, const float* __restrict__ ss,
                                    int F, size_t total4) {
  size_t i = (size_t)blockIdx.x * blockDim.x + threadIdx.x;
  size_t stride = (size_t)gridDim.x * blockDim.x;
  for (; i < total4; i += stride) {
    int c = (int)((i * 4) & (size_t)(F - 1));
    ushort4 u = ((ushort4*)x)[i];
    float v0 = b2f(u.x) * ss[c + 0] + ss[F + c + 0];
    float v1 = b2f(u.y) * ss[c + 1] + ss[F + c + 1];
    float v2 = b2f(u.z) * ss[c + 2] + ss[F + c + 2];
    float v3 = b2f(u.w) * ss[c + 3] + ss[F + c + 3];
    v0 = v0 > 0.f ? v0 : expm1f(v0);
    v1 = v1 > 0.f ? v1 : expm1f(v1);
    v2 = v2 > 0.f ? v2 : expm1f(v2);
    v3 = v3 > 0.f ? v3 : expm1f(v3);
    u.x = f2bu(v0); u.y = f2bu(v1); u.z = f2bu(v2); u.w = f2bu(v3);
    ((ushort4*)x)[i] = u;
  }
}

// ---------------- gather layer 2: online softmax, chunk-4 double-buffered ----------------
#define G2_LOAD(i, rv, ev)                                                     \
  if ((i) < e) {                                                               \
    int ssrc = elist[(i)];                                                     \
    ev = leaky(as2[ssrc] + ad);                                                \
    rv = *(const unsigned*)(h2 + (size_t)ssrc * F2 + tid * 2);                 \
  }
#define G2_CONSUME(u, el)                                                      \
  {                                                                            \
    float w;                                                                   \
    if (el > m + RESCALE_THR) {                                                \
      float rr = __expf(m - el);                                               \
      z *= rr; a0 *= rr; a1 *= rr;                                             \
      m = el; w = 1.f;                                                         \
    } else {                                                                   \
      w = __expf(el - m);                                                      \
    }                                                                          \
    z += w;                                                                    \
    a0 += w * __uint_as_float(u << 16);                                        \
    a1 += w * __uint_as_float(u & 0xffff0000u);                                \
  }

__global__ __launch_bounds__(64) void gather2_kernel(const unsigned short* __restrict__ h2,
                                                     const float* __restrict__ as2,
                                                     const float* __restrict__ ad2,
                                                     const int* __restrict__ off,
                                                     const int* __restrict__ elist,
                                                     const float* __restrict__ b2,
                                                     float* __restrict__ out2) {
  int node = blockIdx.x;
  int tid = threadIdx.x;          // 64, 2 channels each
  const float ad = ad2[node];
  int s = off[node], e = off[node + 1];
  float m = leaky(as2[node] + ad);
  float z = 1.f;
  float a0, a1;
  {
    unsigned u = *(const unsigned*)(h2 + (size_t)node * F2 + tid * 2);
    a0 = __uint_as_float(u << 16); a1 = __uint_as_float(u & 0xffff0000u);
  }
  unsigned ra0 = 0, ra1 = 0, ra2 = 0, ra3 = 0;
  float ea0 = 0.f, ea1 = 0.f, ea2 = 0.f, ea3 = 0.f;
  G2_LOAD(s + 0, ra0, ea0)
  G2_LOAD(s + 1, ra1, ea1)
  G2_LOAD(s + 2, ra2, ea2)
  G2_LOAD(s + 3, ra3, ea3)
  for (int base = s; base < e; base += 4) {
    unsigned rb0 = 0, rb1 = 0, rb2 = 0, rb3 = 0;
    float eb0 = 0.f, eb1 = 0.f, eb2 = 0.f, eb3 = 0.f;
    int nb = base + 4;
    G2_LOAD(nb + 0, rb0, eb0)
    G2_LOAD(nb + 1, rb1, eb1)
    G2_LOAD(nb + 2, rb2, eb2)
    G2_LOAD(nb + 3, rb3, eb3)
    G2_CONSUME(ra0, ea0)
    if (base + 1 < e) G2_CONSUME(ra1, ea1)
    if (base + 2 < e) G2_CONSUME(ra2, ea2)
    if (base + 3 < e) G2_CONSUME(ra3, ea3)
    ra0 = rb0; ra1 = rb1; ra2 = rb2; ra3 = rb3;
    ea0 = eb0; ea1 = eb1; ea2 = eb2; ea3 = eb3;
  }
  float inv = 1.f / z;
  float2 o = make_float2(a0 * inv + b2[tid * 2 + 0], a1 * inv + b2[tid * 2 + 1]);
  *(float2*)(out2 + (size_t)node * F2 + tid * 2) = o;
}

// ---------------- classifier head (fused BN2 apply + ELU) ----------------
__global__ __launch_bounds__(64) void cls_kernel(const float* __restrict__ h,
                                                 const float* __restrict__ ss2,
                                                 const float* __restrict__ Wc1,
                                                 const float* __restrict__ bc1,
                                                 const float* __restrict__ Wc2,
                                                 const float* __restrict__ bc2,
                                                 float* __restrict__ out) {
  __shared__ float hl[128];
  int node = blockIdx.x;
  int tid = threadIdx.x;          // 64
  {
    float v = h[(size_t)node * F2 + tid] * ss2[tid] + ss2[F2 + tid];
    v = v > 0.f ? v : expm1f(v);
    hl[tid] = v;
    float v2 = h[(size_t)node * F2 + 64 + tid] * ss2[64 + tid] + ss2[F2 + 64 + tid];
    v2 = v2 > 0.f ? v2 : expm1f(v2);
    hl[tid + 64] = v2;
  }
  __syncthreads();
  float acc = bc1[tid];
#pragma unroll
  for (int k = 0; k < 128; ++k) acc += hl[k] * Wc1[k * 64 + tid];
  acc = fmaxf(acc, 0.f);
  float2 w = *(const float2*)(Wc2 + tid * 2);
  float o0 = acc * w.x, o1 = acc * w.y;
  for (int sh = 32; sh >= 1; sh >>= 1) {
    o0 += __shfl_down(o0, sh, 64);
    o1 += __shfl_down(o1, sh, 64);
  }
  if (tid == 0) {
    out[node * 2 + 0] = o0 + bc2[0];
    out[node * 2 + 1] = o1 + bc2[1];
  }
}

extern "C" void kernel_launch(void* const* d_in, const int* in_sizes, int n_in,
                              void* d_out, int out_size, void* d_ws, size_t ws_size,
                              hipStream_t stream) {
  const float* x        = (const float*)d_in[0];
  const int*   ei_raw   = (const int*)d_in[1];
  const float* W1       = (const float*)d_in[2];
  const float* att_src1 = (const float*)d_in[3];
  const float* att_dst1 = (const float*)d_in[4];
  const float* b1       = (const float*)d_in[5];
  const float* W2       = (const float*)d_in[6];
  const float* att_src2 = (const float*)d_in[7];
  const float* att_dst2 = (const float*)d_in[8];
  const float* b2       = (const float*)d_in[9];
  const float* g1       = (const float*)d_in[10];
  const float* be1      = (const float*)d_in[11];
  const float* g2       = (const float*)d_in[12];
  const float* be2      = (const float*)d_in[13];
  const float* Wc1      = (const float*)d_in[14];
  const float* bc1      = (const float*)d_in[15];
  const float* Wc2      = (const float*)d_in[16];
  const float* bc2      = (const float*)d_in[17];
  float* out = (float*)d_out;

  char* ws = (char*)d_ws;
  size_t o = 0;
  unsigned short* h1b   = (unsigned short*)(ws + o); o += (size_t)N_NODES * F1 * 2;  // 40.96 MB
  unsigned short* out1b = (unsigned short*)(ws + o); o += (size_t)N_NODES * F1 * 2;  // 40.96 MB
  unsigned short* xb    = (unsigned short*)(ws + o); o += (size_t)N_NODES * DIN * 2; // 30.72 MB
  unsigned short* h2b   = (unsigned short*)(ws + o); o += (size_t)N_NODES * F2 * 2;  // 5.12 MB
  float* out2  = (float*)(ws + o); o += (size_t)N_NODES * F2 * 4;                    // 10.24 MB
  float* as1   = (float*)(ws + o); o += (size_t)N_NODES * H1 * 4;
  float* ad1   = (float*)(ws + o); o += (size_t)N_NODES * H1 * 4;
  float* as2   = (float*)(ws + o); o += (size_t)N_NODES * 4;
  float* ad2   = (float*)(ws + o); o += (size_t)N_NODES * 4;
  float* wexpT = (float*)(ws + o); o += (size_t)H1 * N_EDGES * 4;                    // 10.24 MB
  float* zinv  = (float*)(ws + o); o += (size_t)N_NODES * H1 * 4;
  float* wself = (float*)(ws + o); o += (size_t)N_NODES * H1 * 4;
  char*  zbase = ws + o;
  float* bnsum1 = (float*)(ws + o); o += F1 * 2 * 4;
  float* bnsum2 = (float*)(ws + o); o += F2 * 2 * 4;
  int*   deg    = (int*)(ws + o); o += (size_t)N_NODES * 4;
  size_t zbytes = (size_t)((ws + o) - zbase);
  int*   offv   = (int*)(ws + o); o += (size_t)(N_NODES + 4) * 4;
  int*   cursor = (int*)(ws + o); o += (size_t)N_NODES * 4;
  int*   elist  = (int*)(ws + o); o += (size_t)N_EDGES * 4;
  float* ss1    = (float*)(ws + o); o += F1 * 2 * 4;
  float* ss2    = (float*)(ws + o); o += F2 * 2 * 4;
  int*   ei32   = (int*)(ws + o); o += (size_t)2 * N_EDGES * 4;
  unsigned short* W1T = (unsigned short*)(ws + o); o += (size_t)F1 * DIN * 2;
  unsigned short* W2T = (unsigned short*)(ws + o); o += (size_t)F2 * F1 * 2;
  (void)ws_size; (void)in_sizes; (void)n_in; (void)out_size;

  hipMemsetAsync((void*)zbase, 0, zbytes, stream);

  // input conversions
  f2b_kernel<<<2048, 256, 0, stream>>>(x, xb, (size_t)N_NODES * DIN / 4);
  {
    dim3 g1d(F1 / 32, DIN / 32);
    transpose_b_kernel<<<g1d, 256, 0, stream>>>(W1, W1T, DIN, F1);
    dim3 g2d(F2 / 32, F1 / 32);
    transpose_b_kernel<<<g2d, 256, 0, stream>>>(W2, W2T, F1, F2);
  }

  // CSR build
  repack_hist_kernel<<<(2 * N_EDGES + 255) / 256, 256, 0, stream>>>(ei_raw, ei32, deg);
  scan_kernel<<<1, 1024, 0, stream>>>(deg, offv, cursor);
  scatter_kernel<<<(N_EDGES + 255) / 256, 256, 0, stream>>>(ei32, cursor, elist);

  // layer 1: h1 = x @ W1 (bf16 MFMA, fused att logits, XCD panel-affinity swizzle)
  {
    int panels = (N_NODES + GBM - 1) / GBM;          // 157
    int grid1 = ((panels + 7) / 8) * 64;             // 1280
    mfma_gemm_att_kernel<H1, 1><<<grid1, 256, 0, stream>>>(
        xb, W1T, h1b, att_src1, att_dst1, as1, ad1, N_NODES, F1, DIN);
  }
  // Phase A: exact softmax weights per edge/head
  alpha1_kernel<<<N_NODES, 64, 0, stream>>>(as1, ad1, offv, elist, wexpT, zinv, wself);
  // Phase B: weighted gather, head-partitioned (XCD = head)
  gatherw1_kernel<<<dim3(H1, N_NODES), 64, 0, stream>>>(
      h1b, wexpT, zinv, wself, offv, elist, b1, out1b);
  {
    int rows = 79;
    int grid = (N_NODES + rows - 1) / rows;
    bnstats_bf16_kernel<<<grid, 256, 0, stream>>>(out1b, bnsum1, N_NODES, F1, rows);
  }
  bnfinal_kernel<<<(F1 + 255) / 256, 256, 0, stream>>>(bnsum1, g1, be1, ss1, F1);
  bnapply_bf16_kernel<<<2048, 256, 0, stream>>>(out1b, ss1, F1, (size_t)N_NODES * F1 / 4);

  // layer 2: h2 = out1b @ W2 (bf16 MFMA, fused att logits)
  {
    dim3 grid(F2 / GBN, (N_NODES + GBM - 1) / GBM);
    mfma_gemm_att_kernel<1, 0><<<grid, 256, 0, stream>>>(
        out1b, W2T, h2b, att_src2, att_dst2, as2, ad2, N_NODES, F2, F1);
  }
  gather2_kernel<<<N_NODES, 64, 0, stream>>>(h2b, as2, ad2, offv, elist, b2, out2);
  {
    int rows = 79;
    int grid = (N_NODES + rows - 1) / rows;
    bnstats_kernel<1><<<grid, 128, 0, stream>>>(out2, bnsum2, N_NODES, F2, rows);
  }
  bnfinal_kernel<<<1, F2, 0, stream>>>(bnsum2, g2, be2, ss2, F2);

  // classifier (BN2 apply + ELU fused)
  cls_kernel<<<N_NODES, 64, 0, stream>>>(out2, ss2, Wc1, bc1, Wc2, bc2, out);
}

// Round 10
// 447.643 us; speedup vs baseline: 1.0658x; 1.0313x over previous
//
#include <hip/hip_runtime.h>
#include <hip/hip_bf16.h>
#include <math.h>

#define N_NODES 20000
#define N_EDGES 320000
#define DIN 768
#define F1 1024   // H1*C1
#define H1 8
#define C1 128
#define F2 128
#define NEG_SLOPE 0.2f
#define BN_EPS 1e-5f
#define RESCALE_THR 8.0f

typedef __attribute__((ext_vector_type(8))) __bf16 bf16x8;
typedef __attribute__((ext_vector_type(4))) float f32x4;

__device__ __forceinline__ float leaky(float x) { return x > 0.f ? x : NEG_SLOPE * x; }

__device__ __forceinline__ unsigned short f2bu(float x) {
  __hip_bfloat16 b = __float2bfloat16(x);
  return *(unsigned short*)&b;
}
__device__ __forceinline__ float b2f(unsigned short u) {
  return __uint_as_float(((unsigned)u) << 16);
}
__device__ __forceinline__ unsigned pack2(float lo, float hi) {
  return (unsigned)f2bu(lo) | ((unsigned)f2bu(hi) << 16);
}

__device__ __forceinline__ void async_copy16(void* lds, const void* g) {
  __builtin_amdgcn_global_load_lds(
      (const __attribute__((address_space(1))) unsigned int*)g,
      (__attribute__((address_space(3))) unsigned int*)lds, 16, 0, 0);
}

// ---------------- edge_index repack + dst histogram (fused) ----------------
__global__ void repack_hist_kernel(const int* raw, int* ei32, int* deg) {
  int is64 = (raw[1] == 0 && raw[3] == 0 && raw[5] == 0 && raw[7] == 0) ? 1 : 0;
  int e = blockIdx.x * blockDim.x + threadIdx.x;
  if (e < 2 * N_EDGES) {
    int v = is64 ? raw[2 * e] : raw[e];
    ei32[e] = v;
    if (e >= N_EDGES) atomicAdd(&deg[v], 1);   // dst half
  }
}

// single-block scan: 1024 threads x 20 nodes each, 2 barriers total
#define NPT 20
__global__ __launch_bounds__(1024) void scan_kernel(const int* __restrict__ deg,
                                                    int* __restrict__ off,
                                                    int* __restrict__ cursor) {
  __shared__ int wsum[16];
  int tid = threadIdx.x;
  int lane = tid & 63, wv = tid >> 6;
  int base = tid * NPT;
  int loc[NPT];
  int run = 0;
#pragma unroll
  for (int k = 0; k < NPT; ++k) {
    int i = base + k;
    int v = (i < N_NODES) ? deg[i] : 0;
    loc[k] = run;
    run += v;
  }
  int incl = run;
  for (int sh = 1; sh < 64; sh <<= 1) {
    int t = __shfl_up(incl, sh, 64);
    if (lane >= sh) incl += t;
  }
  if (lane == 63) wsum[wv] = incl;
  __syncthreads();
  if (wv == 0 && lane < 16) {
    int v = wsum[lane];
    for (int sh = 1; sh < 16; sh <<= 1) {
      int t = __shfl_up(v, sh, 16);
      if (lane >= sh) v += t;
    }
    wsum[lane] = v;
  }
  __syncthreads();
  int wbase = (wv > 0) ? wsum[wv - 1] : 0;
  int tbase = wbase + incl - run;
#pragma unroll
  for (int k = 0; k < NPT; ++k) {
    int i = base + k;
    if (i < N_NODES) {
      int o = tbase + loc[k];
      off[i] = o;
      cursor[i] = o;
    }
  }
  if (tid == 1023) off[N_NODES] = wbase + incl;
}

__global__ void scatter_kernel(const int* ei, int* cursor, int* elist) {
  int e = blockIdx.x * blockDim.x + threadIdx.x;
  if (e < N_EDGES) {
    int dst = ei[N_EDGES + e];
    int p = atomicAdd(&cursor[dst], 1);
    elist[p] = ei[e];
  }
}

// ---------------- fp32 -> bf16 convert ----------------
__global__ void f2b_kernel(const float* __restrict__ in, unsigned short* __restrict__ out,
                           size_t n4) {
  size_t i = (size_t)blockIdx.x * blockDim.x + threadIdx.x;
  size_t stride = (size_t)gridDim.x * blockDim.x;
  for (; i < n4; i += stride) {
    float4 v = ((const float4*)in)[i];
    ushort4 u;
    u.x = f2bu(v.x); u.y = f2bu(v.y); u.z = f2bu(v.z); u.w = f2bu(v.w);
    ((ushort4*)out)[i] = u;
  }
}

// ---------------- transpose + convert: W[K][N] fp32 -> WT[N][K] bf16 ----------------
__global__ void transpose_b_kernel(const float* __restrict__ W, unsigned short* __restrict__ WT,
                                   int K, int N) {
  __shared__ float t[32][33];
  int k0 = blockIdx.y * 32, n0 = blockIdx.x * 32;
  int tx = threadIdx.x & 31, ty = threadIdx.x >> 5;
  for (int i = 0; i < 32; i += 8)
    t[ty + i][tx] = W[(size_t)(k0 + ty + i) * N + n0 + tx];
  __syncthreads();
  for (int i = 0; i < 32; i += 8)
    WT[(size_t)(n0 + ty + i) * K + k0 + tx] = f2bu(t[tx][ty + i]);
}

// ---------------- bf16 MFMA GEMM + fused att-logit epilogue ----------------
#define GBM 128
#define GBN 128
#define GBK 64
template <int H, int SWZ>
__global__ __launch_bounds__(256) void mfma_gemm_att_kernel(
    const unsigned short* __restrict__ A,   // [M][K] bf16
    const unsigned short* __restrict__ BT,  // [N][K] bf16
    unsigned short* __restrict__ C,         // [M][N] bf16
    const float* __restrict__ att_src,      // [N]
    const float* __restrict__ att_dst,      // [N]
    float* __restrict__ as_out,             // [M][H]
    float* __restrict__ ad_out,             // [M][H]
    int M, int N, int K) {
  __shared__ __hip_bfloat16 As[GBM][GBK];
  __shared__ __hip_bfloat16 Bs[GBN][GBK];
  __shared__ float sred[128][2];
  __shared__ float dred[128][2];
  int bx, by;
  if (SWZ) {
    int bid = blockIdx.x;
    int pl = bid & 7, c = (bid >> 3) & 7, ph = bid >> 6;
    int p = ph * 8 + pl;
    if (p * GBM >= M) return;
    by = p; bx = c;
  } else {
    bx = blockIdx.x; by = blockIdx.y;
  }
  int tid = threadIdx.x;
  int lane = tid & 63, wid = tid >> 6;
  int wr = wid >> 1, wc = wid & 1;                // 2x2 wave grid, 64x64 out each
  int row0 = by * GBM, col0 = bx * GBN;
  int head = bx;                                  // col-tile == head (H tiles)
  int l16 = lane & 15, l4 = lane >> 4;
  f32x4 acc[4][4] = {};
  for (int k0 = 0; k0 < K; k0 += GBK) {
#pragma unroll
    for (int j = 0; j < 4; ++j) {
      int c = j * 256 + tid;
      int r = c >> 3, kk = (c & 7) << 3;
      int ga = row0 + r; if (ga >= M) ga = M - 1;
      async_copy16(&As[r][kk], A + (size_t)ga * K + k0 + kk);
      async_copy16(&Bs[r][kk], BT + (size_t)(col0 + r) * K + k0 + kk);
    }
    __syncthreads();
#pragma unroll
    for (int ks = 0; ks < 2; ++ks) {
      bf16x8 af[4], bfr[4];
#pragma unroll
      for (int i = 0; i < 4; ++i)
        af[i] = *(const bf16x8*)&As[wr * 64 + i * 16 + l16][ks * 32 + l4 * 8];
#pragma unroll
      for (int j = 0; j < 4; ++j)
        bfr[j] = *(const bf16x8*)&Bs[wc * 64 + j * 16 + l16][ks * 32 + l4 * 8];
#pragma unroll
      for (int i = 0; i < 4; ++i)
#pragma unroll
        for (int j = 0; j < 4; ++j)
          acc[i][j] = __builtin_amdgcn_mfma_f32_16x16x32_bf16(af[i], bfr[j], acc[i][j], 0, 0, 0);
    }
    __syncthreads();
  }
  // ---- C store (bf16): col=lane&15, row=(lane>>4)*4+r ----
#pragma unroll
  for (int i = 0; i < 4; ++i) {
#pragma unroll
    for (int j = 0; j < 4; ++j) {
#pragma unroll
      for (int r = 0; r < 4; ++r) {
        int row = row0 + wr * 64 + i * 16 + l4 * 4 + r;
        int col = col0 + wc * 64 + j * 16 + l16;
        if (row < M) C[(size_t)row * N + col] = f2bu(acc[i][j][r]);
      }
    }
  }
  // ---- fused attention logits from fp32 accumulators ----
  float avs[4], avd[4];
#pragma unroll
  for (int j = 0; j < 4; ++j) {
    int col = col0 + wc * 64 + j * 16 + l16;
    avs[j] = att_src[col];
    avd[j] = att_dst[col];
  }
#pragma unroll
  for (int i = 0; i < 4; ++i) {
#pragma unroll
    for (int r = 0; r < 4; ++r) {
      float ps = 0.f, pd = 0.f;
#pragma unroll
      for (int j = 0; j < 4; ++j) { ps += acc[i][j][r] * avs[j]; pd += acc[i][j][r] * avd[j]; }
#pragma unroll
      for (int mk = 1; mk < 16; mk <<= 1) {
        ps += __shfl_xor(ps, mk, 64);
        pd += __shfl_xor(pd, mk, 64);
      }
      if (l16 == 0) {
        int lr = wr * 64 + i * 16 + l4 * 4 + r;
        sred[lr][wc] = ps;
        dred[lr][wc] = pd;
      }
    }
  }
  __syncthreads();
  if (tid < 128) {
    int row = row0 + tid;
    if (row < M) {
      as_out[(size_t)row * H + head] = sred[tid][0] + sred[tid][1];
      ad_out[(size_t)row * H + head] = dred[tid][0] + dred[tid][1];
    }
  }
}

// ---------------- Phase A: all-heads softmax weights, single edge traversal ----------------
// One 64-lane block per node. Lane i handles edges s+i, s+i+64, ...
// Per edge: ONE as1-row load (32B) -> 8 logits. Pass 1 max, pass 2 exp+store
// fused {src, w} per head stream: ewT[h][i] = (uint2){src, bits(w)}.
__global__ __launch_bounds__(64) void alpha1_kernel(const float* __restrict__ as1,
                                                    const float* __restrict__ ad1,
                                                    const int* __restrict__ off,
                                                    const int* __restrict__ elist,
                                                    uint2* __restrict__ ewT,     // [H1][E]
                                                    float* __restrict__ zinv,    // [N][H1]
                                                    float* __restrict__ wself) { // [N][H1]
  int node = blockIdx.x;
  int lane = threadIdx.x;
  int s = off[node], e = off[node + 1];
  float4 adlo = *(const float4*)(ad1 + node * H1);
  float4 adhi = *(const float4*)(ad1 + node * H1 + 4);
  float ad[8] = {adlo.x, adlo.y, adlo.z, adlo.w, adhi.x, adhi.y, adhi.z, adhi.w};
  float4 aslo = *(const float4*)(as1 + node * H1);
  float4 ashi = *(const float4*)(as1 + node * H1 + 4);
  float sl[8] = {aslo.x, aslo.y, aslo.z, aslo.w, ashi.x, ashi.y, ashi.z, ashi.w};
  float m[8];
#pragma unroll
  for (int h = 0; h < 8; ++h) { sl[h] = leaky(sl[h] + ad[h]); m[h] = sl[h]; }
  // pass 1: per-head max over edges
  for (int i = s + lane; i < e; i += 64) {
    int src = elist[i];
    float4 lo = *(const float4*)(as1 + (size_t)src * H1);
    float4 hi = *(const float4*)(as1 + (size_t)src * H1 + 4);
    float v[8] = {lo.x, lo.y, lo.z, lo.w, hi.x, hi.y, hi.z, hi.w};
#pragma unroll
    for (int h = 0; h < 8; ++h) m[h] = fmaxf(m[h], leaky(v[h] + ad[h]));
  }
#pragma unroll
  for (int h = 0; h < 8; ++h)
    for (int sh = 32; sh >= 1; sh >>= 1) m[h] = fmaxf(m[h], __shfl_xor(m[h], sh, 64));
  // pass 2: weights (fused {src,w}) + z
  float z[8] = {0.f, 0.f, 0.f, 0.f, 0.f, 0.f, 0.f, 0.f};
  for (int i = s + lane; i < e; i += 64) {
    int src = elist[i];
    float4 lo = *(const float4*)(as1 + (size_t)src * H1);
    float4 hi = *(const float4*)(as1 + (size_t)src * H1 + 4);
    float v[8] = {lo.x, lo.y, lo.z, lo.w, hi.x, hi.y, hi.z, hi.w};
#pragma unroll
    for (int h = 0; h < 8; ++h) {
      float w = __expf(leaky(v[h] + ad[h]) - m[h]);
      z[h] += w;
      ewT[(size_t)h * N_EDGES + i] = make_uint2((unsigned)src, __float_as_uint(w));
    }
  }
#pragma unroll
  for (int h = 0; h < 8; ++h)
    for (int sh = 32; sh >= 1; sh >>= 1) z[h] += __shfl_xor(z[h], sh, 64);
  if (lane == 0) {
#pragma unroll
    for (int h = 0; h < 8; ++h) {
      float ws = __expf(sl[h] - m[h]);
      zinv[node * H1 + h] = 1.f / (z[h] + ws);
      wself[node * H1 + h] = ws;
    }
  }
}

// ---------------- Phase B: weighted gather, head-partitioned, fused ew stream ----------------
// grid (H1, N_NODES): XCD = head (L2-local h1 slice). Inner loop: 2 VMEM/edge
// ({src,w} uint2 + 4B h1 row slice), 4-edge groups, double-buffered.
#define EW_LOAD(i, ev)                                                          \
  if ((i) < e) ev = ewp[(i)];
#define H1_LOAD(i, ev, rv)                                                      \
  if ((i) < e) rv = *(const unsigned*)(h1 + (size_t)ev.x * F1 + cb);
#define GW_CONS(u, ev)                                                          \
  {                                                                             \
    float wv = __uint_as_float(ev.y);                                           \
    a0 += wv * __uint_as_float(u << 16);                                        \
    a1 += wv * __uint_as_float(u & 0xffff0000u);                                \
  }

__global__ __launch_bounds__(64) void gatherw1_kernel(const unsigned short* __restrict__ h1,
                                                      const uint2* __restrict__ ewT,
                                                      const float* __restrict__ zinv,
                                                      const float* __restrict__ wself,
                                                      const int* __restrict__ off,
                                                      const float* __restrict__ b1,
                                                      unsigned short* __restrict__ out1) {
  int head = blockIdx.x;           // 0..7 -> XCD affinity
  int node = blockIdx.y;
  int tid = threadIdx.x;           // 64 lanes, 2 channels each
  int cb = head * C1 + tid * 2;
  int s = off[node], e = off[node + 1];
  const uint2* ewp = ewT + (size_t)head * N_EDGES;
  float a0, a1;
  {
    float ws = wself[node * H1 + head];
    unsigned u = *(const unsigned*)(h1 + (size_t)node * F1 + cb);
    a0 = ws * __uint_as_float(u << 16);
    a1 = ws * __uint_as_float(u & 0xffff0000u);
  }
  uint2 ea0 = {0, 0}, ea1 = {0, 0}, ea2 = {0, 0}, ea3 = {0, 0};
  uint2 eb0 = {0, 0}, eb1 = {0, 0}, eb2 = {0, 0}, eb3 = {0, 0};
  unsigned ra0 = 0, ra1 = 0, ra2 = 0, ra3 = 0;
  EW_LOAD(s + 0, ea0)
  EW_LOAD(s + 1, ea1)
  EW_LOAD(s + 2, ea2)
  EW_LOAD(s + 3, ea3)
  EW_LOAD(s + 4, eb0)
  EW_LOAD(s + 5, eb1)
  EW_LOAD(s + 6, eb2)
  EW_LOAD(s + 7, eb3)
  H1_LOAD(s + 0, ea0, ra0)
  H1_LOAD(s + 1, ea1, ra1)
  H1_LOAD(s + 2, ea2, ra2)
  H1_LOAD(s + 3, ea3, ra3)
  for (int base = s; base < e; base += 4) {
    unsigned rb0 = 0, rb1 = 0, rb2 = 0, rb3 = 0;
    int nb = base + 4;
    H1_LOAD(nb + 0, eb0, rb0)
    H1_LOAD(nb + 1, eb1, rb1)
    H1_LOAD(nb + 2, eb2, rb2)
    H1_LOAD(nb + 3, eb3, rb3)
    uint2 ec0 = {0, 0}, ec1 = {0, 0}, ec2 = {0, 0}, ec3 = {0, 0};
    int nc = base + 8;
    EW_LOAD(nc + 0, ec0)
    EW_LOAD(nc + 1, ec1)
    EW_LOAD(nc + 2, ec2)
    EW_LOAD(nc + 3, ec3)
    GW_CONS(ra0, ea0)
    GW_CONS(ra1, ea1)
    GW_CONS(ra2, ea2)
    GW_CONS(ra3, ea3)
    ea0 = eb0; ea1 = eb1; ea2 = eb2; ea3 = eb3;
    eb0 = ec0; eb1 = ec1; eb2 = ec2; eb3 = ec3;
    ra0 = rb0; ra1 = rb1; ra2 = rb2; ra3 = rb3;
  }
  float inv = zinv[node * H1 + head];
  float2 bv = *(const float2*)(b1 + cb);
  unsigned o = pack2(a0 * inv + bv.x, a1 * inv + bv.y);
  *(unsigned*)(out1 + (size_t)node * F1 + cb) = o;
}

// ---------------- BN statistics, bf16 input ----------------
__global__ void bnstats_bf16_kernel(const unsigned short* __restrict__ x,
                                    float* __restrict__ sums,
                                    int nrows, int F, int rowsPerBlock) {
  int tid = threadIdx.x;
  int c = tid * 4;
  int r0 = blockIdx.x * rowsPerBlock;
  int rend = min(r0 + rowsPerBlock, nrows);
  float s0 = 0.f, s1 = 0.f, s2 = 0.f, s3 = 0.f;
  float q0 = 0.f, q1 = 0.f, q2 = 0.f, q3 = 0.f;
  for (int r = r0; r < rend; ++r) {
    ushort4 u = *(const ushort4*)(x + (size_t)r * F + c);
    float v0 = b2f(u.x), v1 = b2f(u.y), v2 = b2f(u.z), v3 = b2f(u.w);
    s0 += v0; s1 += v1; s2 += v2; s3 += v3;
    q0 += v0 * v0; q1 += v1 * v1; q2 += v2 * v2; q3 += v3 * v3;
  }
  atomicAdd(&sums[c + 0], s0); atomicAdd(&sums[c + 1], s1);
  atomicAdd(&sums[c + 2], s2); atomicAdd(&sums[c + 3], s3);
  atomicAdd(&sums[F + c + 0], q0); atomicAdd(&sums[F + c + 1], q1);
  atomicAdd(&sums[F + c + 2], q2); atomicAdd(&sums[F + c + 3], q3);
}

// fp32-input variant (layer 2, small)
template <int CPT>
__global__ void bnstats_kernel(const float* __restrict__ x, float* __restrict__ sums,
                               int nrows, int F, int rowsPerBlock) {
  int tid = threadIdx.x;
  int r0 = blockIdx.x * rowsPerBlock;
  int rend = min(r0 + rowsPerBlock, nrows);
  float s[CPT], q[CPT];
#pragma unroll
  for (int k = 0; k < CPT; ++k) { s[k] = 0.f; q[k] = 0.f; }
  for (int r = r0; r < rend; ++r) {
    const float* row = x + (size_t)r * F;
#pragma unroll
    for (int k = 0; k < CPT; ++k) {
      float v = row[tid + k * blockDim.x];
      s[k] += v; q[k] += v * v;
    }
  }
#pragma unroll
  for (int k = 0; k < CPT; ++k) {
    atomicAdd(&sums[tid + k * blockDim.x], s[k]);
    atomicAdd(&sums[F + tid + k * blockDim.x], q[k]);
  }
}

__global__ void bnfinal_kernel(const float* __restrict__ sums, const float* __restrict__ g,
                               const float* __restrict__ be, float* __restrict__ ss, int F) {
  int c = blockIdx.x * blockDim.x + threadIdx.x;
  if (c < F) {
    float mu = sums[c] * (1.f / N_NODES);
    float var = sums[F + c] * (1.f / N_NODES) - mu * mu;
    float sc = g[c] * rsqrtf(var + BN_EPS);
    ss[c] = sc;
    ss[F + c] = be[c] - mu * sc;
  }
}

// BN apply + ELU, bf16 in-place (layer 1, feeds GEMM2)
__global__ void bnapply_bf16_kernel(unsigned short* __restrict__ x, const float* __restrict__ ss,
                                    int F, size_t total4) {
  size_t i = (size_t)blockIdx.x * blockDim.x + threadIdx.x;
  size_t stride = (size_t)gridDim.x * blockDim.x;
  for (; i < total4; i += stride) {
    int c = (int)((i * 4) & (size_t)(F - 1));
    ushort4 u = ((ushort4*)x)[i];
    float v0 = b2f(u.x) * ss[c + 0] + ss[F + c + 0];
    float v1 = b2f(u.y) * ss[c + 1] + ss[F + c + 1];
    float v2 = b2f(u.z) * ss[c + 2] + ss[F + c + 2];
    float v3 = b2f(u.w) * ss[c + 3] + ss[F + c + 3];
    v0 = v0 > 0.f ? v0 : expm1f(v0);
    v1 = v1 > 0.f ? v1 : expm1f(v1);
    v2 = v2 > 0.f ? v2 : expm1f(v2);
    v3 = v3 > 0.f ? v3 : expm1f(v3);
    u.x = f2bu(v0); u.y = f2bu(v1); u.z = f2bu(v2); u.w = f2bu(v3);
    ((ushort4*)x)[i] = u;
  }
}

// ---------------- gather layer 2: online softmax, chunk-4 double-buffered ----------------
#define G2_LOAD(i, rv, ev)                                                     \
  if ((i) < e) {                                                               \
    int ssrc = elist[(i)];                                                     \
    ev = leaky(as2[ssrc] + ad);                                                \
    rv = *(const unsigned*)(h2 + (size_t)ssrc * F2 + tid * 2);                 \
  }
#define G2_CONSUME(u, el)                                                      \
  {                                                                            \
    float w;                                                                   \
    if (el > m + RESCALE_THR) {                                                \
      float rr = __expf(m - el);                                               \
      z *= rr; a0 *= rr; a1 *= rr;                                             \
      m = el; w = 1.f;                                                         \
    } else {                                                                   \
      w = __expf(el - m);                                                      \
    }                                                                          \
    z += w;                                                                    \
    a0 += w * __uint_as_float(u << 16);                                        \
    a1 += w * __uint_as_float(u & 0xffff0000u);                                \
  }

__global__ __launch_bounds__(64) void gather2_kernel(const unsigned short* __restrict__ h2,
                                                     const float* __restrict__ as2,
                                                     const float* __restrict__ ad2,
                                                     const int* __restrict__ off,
                                                     const int* __restrict__ elist,
                                                     const float* __restrict__ b2,
                                                     float* __restrict__ out2) {
  int node = blockIdx.x;
  int tid = threadIdx.x;          // 64, 2 channels each
  const float ad = ad2[node];
  int s = off[node], e = off[node + 1];
  float m = leaky(as2[node] + ad);
  float z = 1.f;
  float a0, a1;
  {
    unsigned u = *(const unsigned*)(h2 + (size_t)node * F2 + tid * 2);
    a0 = __uint_as_float(u << 16); a1 = __uint_as_float(u & 0xffff0000u);
  }
  unsigned ra0 = 0, ra1 = 0, ra2 = 0, ra3 = 0;
  float ea0 = 0.f, ea1 = 0.f, ea2 = 0.f, ea3 = 0.f;
  G2_LOAD(s + 0, ra0, ea0)
  G2_LOAD(s + 1, ra1, ea1)
  G2_LOAD(s + 2, ra2, ea2)
  G2_LOAD(s + 3, ra3, ea3)
  for (int base = s; base < e; base += 4) {
    unsigned rb0 = 0, rb1 = 0, rb2 = 0, rb3 = 0;
    float eb0 = 0.f, eb1 = 0.f, eb2 = 0.f, eb3 = 0.f;
    int nb = base + 4;
    G2_LOAD(nb + 0, rb0, eb0)
    G2_LOAD(nb + 1, rb1, eb1)
    G2_LOAD(nb + 2, rb2, eb2)
    G2_LOAD(nb + 3, rb3, eb3)
    G2_CONSUME(ra0, ea0)
    if (base + 1 < e) G2_CONSUME(ra1, ea1)
    if (base + 2 < e) G2_CONSUME(ra2, ea2)
    if (base + 3 < e) G2_CONSUME(ra3, ea3)
    ra0 = rb0; ra1 = rb1; ra2 = rb2; ra3 = rb3;
    ea0 = eb0; ea1 = eb1; ea2 = eb2; ea3 = eb3;
  }
  float inv = 1.f / z;
  float2 o = make_float2(a0 * inv + b2[tid * 2 + 0], a1 * inv + b2[tid * 2 + 1]);
  *(float2*)(out2 + (size_t)node * F2 + tid * 2) = o;
}

// ---------------- classifier head (fused BN2 apply + ELU) ----------------
__global__ __launch_bounds__(64) void cls_kernel(const float* __restrict__ h,
                                                 const float* __restrict__ ss2,
                                                 const float* __restrict__ Wc1,
                                                 const float* __restrict__ bc1,
                                                 const float* __restrict__ Wc2,
                                                 const float* __restrict__ bc2,
                                                 float* __restrict__ out) {
  __shared__ float hl[128];
  int node = blockIdx.x;
  int tid = threadIdx.x;          // 64
  {
    float v = h[(size_t)node * F2 + tid] * ss2[tid] + ss2[F2 + tid];
    v = v > 0.f ? v : expm1f(v);
    hl[tid] = v;
    float v2 = h[(size_t)node * F2 + 64 + tid] * ss2[64 + tid] + ss2[F2 + 64 + tid];
    v2 = v2 > 0.f ? v2 : expm1f(v2);
    hl[tid + 64] = v2;
  }
  __syncthreads();
  float acc = bc1[tid];
#pragma unroll
  for (int k = 0; k < 128; ++k) acc += hl[k] * Wc1[k * 64 + tid];
  acc = fmaxf(acc, 0.f);
  float2 w = *(const float2*)(Wc2 + tid * 2);
  float o0 = acc * w.x, o1 = acc * w.y;
  for (int sh = 32; sh >= 1; sh >>= 1) {
    o0 += __shfl_down(o0, sh, 64);
    o1 += __shfl_down(o1, sh, 64);
  }
  if (tid == 0) {
    out[node * 2 + 0] = o0 + bc2[0];
    out[node * 2 + 1] = o1 + bc2[1];
  }
}

extern "C" void kernel_launch(void* const* d_in, const int* in_sizes, int n_in,
                              void* d_out, int out_size, void* d_ws, size_t ws_size,
                              hipStream_t stream) {
  const float* x        = (const float*)d_in[0];
  const int*   ei_raw   = (const int*)d_in[1];
  const float* W1       = (const float*)d_in[2];
  const float* att_src1 = (const float*)d_in[3];
  const float* att_dst1 = (const float*)d_in[4];
  const float* b1       = (const float*)d_in[5];
  const float* W2       = (const float*)d_in[6];
  const float* att_src2 = (const float*)d_in[7];
  const float* att_dst2 = (const float*)d_in[8];
  const float* b2       = (const float*)d_in[9];
  const float* g1       = (const float*)d_in[10];
  const float* be1      = (const float*)d_in[11];
  const float* g2       = (const float*)d_in[12];
  const float* be2      = (const float*)d_in[13];
  const float* Wc1      = (const float*)d_in[14];
  const float* bc1      = (const float*)d_in[15];
  const float* Wc2      = (const float*)d_in[16];
  const float* bc2      = (const float*)d_in[17];
  float* out = (float*)d_out;

  char* ws = (char*)d_ws;
  size_t o = 0;
  unsigned short* h1b   = (unsigned short*)(ws + o); o += (size_t)N_NODES * F1 * 2;  // 40.96 MB
  unsigned short* out1b = (unsigned short*)(ws + o); o += (size_t)N_NODES * F1 * 2;  // 40.96 MB
  unsigned short* xb    = (unsigned short*)(ws + o); o += (size_t)N_NODES * DIN * 2; // 30.72 MB
  unsigned short* h2b   = (unsigned short*)(ws + o); o += (size_t)N_NODES * F2 * 2;  // 5.12 MB
  float* out2  = (float*)(ws + o); o += (size_t)N_NODES * F2 * 4;                    // 10.24 MB
  float* as1   = (float*)(ws + o); o += (size_t)N_NODES * H1 * 4;
  float* ad1   = (float*)(ws + o); o += (size_t)N_NODES * H1 * 4;
  float* as2   = (float*)(ws + o); o += (size_t)N_NODES * 4;
  float* ad2   = (float*)(ws + o); o += (size_t)N_NODES * 4;
  uint2* ewT   = (uint2*)(ws + o); o += (size_t)H1 * N_EDGES * 8;                    // 20.48 MB
  float* zinv  = (float*)(ws + o); o += (size_t)N_NODES * H1 * 4;
  float* wself = (float*)(ws + o); o += (size_t)N_NODES * H1 * 4;
  char*  zbase = ws + o;
  float* bnsum1 = (float*)(ws + o); o += F1 * 2 * 4;
  float* bnsum2 = (float*)(ws + o); o += F2 * 2 * 4;
  int*   deg    = (int*)(ws + o); o += (size_t)N_NODES * 4;
  size_t zbytes = (size_t)((ws + o) - zbase);
  int*   offv   = (int*)(ws + o); o += (size_t)(N_NODES + 4) * 4;
  int*   cursor = (int*)(ws + o); o += (size_t)N_NODES * 4;
  int*   elist  = (int*)(ws + o); o += (size_t)N_EDGES * 4;
  float* ss1    = (float*)(ws + o); o += F1 * 2 * 4;
  float* ss2    = (float*)(ws + o); o += F2 * 2 * 4;
  int*   ei32   = (int*)(ws + o); o += (size_t)2 * N_EDGES * 4;
  unsigned short* W1T = (unsigned short*)(ws + o); o += (size_t)F1 * DIN * 2;
  unsigned short* W2T = (unsigned short*)(ws + o); o += (size_t)F2 * F1 * 2;
  (void)ws_size; (void)in_sizes; (void)n_in; (void)out_size;

  hipMemsetAsync((void*)zbase, 0, zbytes, stream);

  // input conversions
  f2b_kernel<<<2048, 256, 0, stream>>>(x, xb, (size_t)N_NODES * DIN / 4);
  {
    dim3 g1d(F1 / 32, DIN / 32);
    transpose_b_kernel<<<g1d, 256, 0, stream>>>(W1, W1T, DIN, F1);
    dim3 g2d(F2 / 32, F1 / 32);
    transpose_b_kernel<<<g2d, 256, 0, stream>>>(W2, W2T, F1, F2);
  }

  // CSR build
  repack_hist_kernel<<<(2 * N_EDGES + 255) / 256, 256, 0, stream>>>(ei_raw, ei32, deg);
  scan_kernel<<<1, 1024, 0, stream>>>(deg, offv, cursor);
  scatter_kernel<<<(N_EDGES + 255) / 256, 256, 0, stream>>>(ei32, cursor, elist);

  // layer 1: h1 = x @ W1 (bf16 MFMA, fused att logits, XCD panel-affinity swizzle)
  {
    int panels = (N_NODES + GBM - 1) / GBM;          // 157
    int grid1 = ((panels + 7) / 8) * 64;             // 1280
    mfma_gemm_att_kernel<H1, 1><<<grid1, 256, 0, stream>>>(
        xb, W1T, h1b, att_src1, att_dst1, as1, ad1, N_NODES, F1, DIN);
  }
  // Phase A: all-heads softmax weights, single traversal
  alpha1_kernel<<<N_NODES, 64, 0, stream>>>(as1, ad1, offv, elist, ewT, zinv, wself);
  // Phase B: weighted gather, head-partitioned (XCD = head), fused ew stream
  gatherw1_kernel<<<dim3(H1, N_NODES), 64, 0, stream>>>(
      h1b, ewT, zinv, wself, offv, b1, out1b);
  {
    int rows = 79;
    int grid = (N_NODES + rows - 1) / rows;
    bnstats_bf16_kernel<<<grid, 256, 0, stream>>>(out1b, bnsum1, N_NODES, F1, rows);
  }
  bnfinal_kernel<<<(F1 + 255) / 256, 256, 0, stream>>>(bnsum1, g1, be1, ss1, F1);
  bnapply_bf16_kernel<<<2048, 256, 0, stream>>>(out1b, ss1, F1, (size_t)N_NODES * F1 / 4);

  // layer 2: h2 = out1b @ W2 (bf16 MFMA, fused att logits)
  {
    dim3 grid(F2 / GBN, (N_NODES + GBM - 1) / GBM);
    mfma_gemm_att_kernel<1, 0><<<grid, 256, 0, stream>>>(
        out1b, W2T, h2b, att_src2, att_dst2, as2, ad2, N_NODES, F2, F1);
  }
  gather2_kernel<<<N_NODES, 64, 0, stream>>>(h2b, as2, ad2, offv, elist, b2, out2);
  {
    int rows = 79;
    int grid = (N_NODES + rows - 1) / rows;
    bnstats_kernel<1><<<grid, 128, 0, stream>>>(out2, bnsum2, N_NODES, F2, rows);
  }
  bnfinal_kernel<<<1, F2, 0, stream>>>(bnsum2, g2, be2, ss2, F2);

  // classifier (BN2 apply + ELU fused)
  cls_kernel<<<N_NODES, 64, 0, stream>>>(out2, ss2, Wc1, bc1, Wc2, bc2, out);
}